// Round 19
// baseline (103.089 us; speedup 1.0000x reference)
//
#include <hip/hip_runtime.h>
#include <hip/hip_bf16.h>

#define DI 512
#define DM 512
#define NBATCH 4
#define NL 2048
#define NH 8
#define NE 64
#define NBH 32   // NBATCH*NH

typedef __attribute__((ext_vector_type(8))) short bf16x8;
typedef __attribute__((ext_vector_type(4))) short bf16x4;
typedef __attribute__((ext_vector_type(4))) float f32x4;
typedef __attribute__((ext_vector_type(4))) float fx4;
typedef __attribute__((ext_vector_type(4))) unsigned int u32x4;
typedef unsigned short u16;

__device__ __forceinline__ u16 f2bf(float f) {
  union { float f; unsigned int u; } v; v.f = f;
  unsigned int r = v.u + 0x7fffu + ((v.u >> 16) & 1u);
  return (u16)(r >> 16);
}

__device__ __forceinline__ unsigned int packbf(float lo, float hi) {
  const unsigned int l = __float_as_uint(lo) + 0x8000u;
  const unsigned int h = __float_as_uint(hi) + 0x8000u;
  return (h & 0xFFFF0000u) | (l >> 16);
}

// ---- weight transpose + f32->bf16, all 4 weights in one launch ----
__global__ __launch_bounds__(256) void wt_kernel(
    const float* __restrict__ W0, const float* __restrict__ W1,
    const float* __restrict__ W2, const float* __restrict__ W3,
    u16* __restrict__ T0, u16* __restrict__ T1, u16* __restrict__ T2,
    u16* __restrict__ T3) {
  const int z = blockIdx.z;
  const float* W = z == 0 ? W0 : z == 1 ? W1 : z == 2 ? W2 : W3;
  u16* Wt = z == 0 ? T0 : z == 1 ? T1 : z == 2 ? T2 : T3;
  __shared__ float t[32][33];
  const int bk = blockIdx.x * 32;
  const int bn = blockIdx.y * 32;
  const int x = threadIdx.x & 31;
  const int y0 = (threadIdx.x >> 5) * 4;
#pragma unroll
  for (int i = 0; i < 4; i++)
    t[y0 + i][x] = W[(size_t)(bk + y0 + i) * 512 + bn + x];
  __syncthreads();
#pragma unroll
  for (int i = 0; i < 4; i++)
    Wt[(size_t)(bn + y0 + i) * 512 + bk + x] = f2bf(t[x][y0 + i]);
}

// ---- QKV projections: 64x128 tile, 512 threads / 8 waves (R18-proven) ----
__global__ __launch_bounds__(512) void qkv_kernel(
    const float* __restrict__ Aq, const float* __restrict__ Ak,
    const float* __restrict__ Av, const u16* __restrict__ Bq,
    const u16* __restrict__ Bk, const u16* __restrict__ Bv,
    const float* __restrict__ biq, const float* __restrict__ bik,
    const float* __restrict__ biv, u16* __restrict__ oq,
    u16* __restrict__ ok, u16* __restrict__ ov) {
  const int z = blockIdx.z;
  const float* A = z == 0 ? Aq : z == 1 ? Ak : Av;
  const u16* Bt = z == 0 ? Bq : z == 1 ? Bk : Bv;
  const float* bias = z == 0 ? biq : z == 1 ? bik : biv;
  u16* Cptr = z == 0 ? oq : z == 1 ? ok : ov;
  const float scale = z == 0 ? 0.1803368867f : 1.0f;  // 0.125/ln(2) for q

  __shared__ u16 Alds[64][72];
  __shared__ u16 Blds[128][72];
  const int tid = threadIdx.x;
  const int w = tid >> 6, lane = tid & 63;
  const int g = lane >> 4, lc = lane & 15;
  const int bm = blockIdx.x * 64;
  const int bn = blockIdx.y * 128;
  const int wm = (w >> 2) * 32;
  const int wn = (w & 3) * 32;

  f32x4 acc[2][2];
#pragma unroll
  for (int i = 0; i < 2; i++)
#pragma unroll
    for (int j = 0; j < 2; j++) acc[i][j] = (f32x4){0.f, 0.f, 0.f, 0.f};

  const int ar = tid >> 3, ac = (tid & 7) * 8;    // A: 64 rows, 8 f32/thr
  const int br = tid >> 2, bc = (tid & 3) * 16;   // B: 128 rows, 16 bf16/thr

  const float* asrc = A + (size_t)(bm + ar) * 512 + ac;
  const u16* bsrc = Bt + (size_t)(bn + br) * 512 + bc;

  fx4 fA0 = *(const fx4*)asrc;
  fx4 fA1 = *(const fx4*)(asrc + 4);
  u32x4 fB0 = *(const u32x4*)bsrc;
  u32x4 fB1 = *(const u32x4*)(bsrc + 8);

#pragma unroll
  for (int ti = 0; ti < 8; ++ti) {
    __syncthreads();  // prev compute's LDS reads complete
    {
      u32x4 out;
      out[0] = packbf(fA0[0], fA0[1]);
      out[1] = packbf(fA0[2], fA0[3]);
      out[2] = packbf(fA1[0], fA1[1]);
      out[3] = packbf(fA1[2], fA1[3]);
      *(u32x4*)&Alds[ar][ac] = out;
      *(u32x4*)&Blds[br][bc] = fB0;
      *(u32x4*)&Blds[br][bc + 8] = fB1;
    }
    __syncthreads();  // writes visible
    if (ti + 1 < 8) {  // issue next-tile loads; hide under compute
      const float* an = asrc + (ti + 1) * 64;
      fA0 = *(const fx4*)an;
      fA1 = *(const fx4*)(an + 4);
      const u16* bn2 = bsrc + (ti + 1) * 64;
      fB0 = *(const u32x4*)bn2;
      fB1 = *(const u32x4*)(bn2 + 8);
    }
#pragma unroll
    for (int kk = 0; kk < 2; kk++) {
      bf16x8 af[2], bf[2];
#pragma unroll
      for (int i = 0; i < 2; i++) {
        af[i] = *(const bf16x8*)&Alds[wm + i * 16 + lc][kk * 32 + g * 8];
        bf[i] = *(const bf16x8*)&Blds[wn + i * 16 + lc][kk * 32 + g * 8];
      }
#pragma unroll
      for (int mi = 0; mi < 2; mi++)
#pragma unroll
        for (int ni = 0; ni < 2; ni++)
          acc[mi][ni] = __builtin_amdgcn_mfma_f32_16x16x32_bf16(
              af[mi], bf[ni], acc[mi][ni], 0, 0, 0);
    }
  }

#pragma unroll
  for (int mi = 0; mi < 2; mi++)
#pragma unroll
    for (int ni = 0; ni < 2; ni++) {
      const int n = bn + wn + ni * 16 + lc;
      const float bv = bias[n];
#pragma unroll
      for (int j = 0; j < 4; j++) {
        const int m = bm + wm + mi * 16 + g * 4 + j;
        float val = (acc[mi][ni][j] + bv) * scale;
        const int b = m >> 11, l = m & 2047;
        const int h = n >> 6, e = n & 63;
        if (z < 2) {
          Cptr[((size_t)(b * NH + h) * NL + l) * NE + e] = f2bf(val);
        } else {
          Cptr[((size_t)(b * NH + h) * NE + e) * NL + l] = f2bf(val);
        }
      }
    }
}

// ---- output projection: 64x128 tile, 512 threads / 8 waves (R18) ----
__global__ __launch_bounds__(512) void gemm_out_kernel(
    const u16* __restrict__ A, const u16* __restrict__ Bt,
    const float* __restrict__ bias, float* __restrict__ Cptr) {
  __shared__ u16 Alds[64][72];
  __shared__ u16 Blds[128][72];
  const int tid = threadIdx.x;
  const int w = tid >> 6, lane = tid & 63;
  const int g = lane >> 4, lc = lane & 15;
  const int bm = blockIdx.x * 64;
  const int bn = blockIdx.y * 128;
  const int wm = (w >> 2) * 32;
  const int wn = (w & 3) * 32;

  f32x4 acc[2][2];
#pragma unroll
  for (int i = 0; i < 2; i++)
#pragma unroll
    for (int j = 0; j < 2; j++) acc[i][j] = (f32x4){0.f, 0.f, 0.f, 0.f};

  const int ar = tid >> 3, ac = (tid & 7) * 8;
  const int br = tid >> 2, bc = (tid & 3) * 16;

  const u16* asrc = A + (size_t)(bm + ar) * 512 + ac;
  const u16* bsrc = Bt + (size_t)(bn + br) * 512 + bc;

  u32x4 gA = *(const u32x4*)asrc;
  u32x4 gB0 = *(const u32x4*)bsrc;
  u32x4 gB1 = *(const u32x4*)(bsrc + 8);

#pragma unroll
  for (int ti = 0; ti < 8; ++ti) {
    __syncthreads();
    {
      *(u32x4*)&Alds[ar][ac] = gA;
      *(u32x4*)&Blds[br][bc] = gB0;
      *(u32x4*)&Blds[br][bc + 8] = gB1;
    }
    __syncthreads();
    if (ti + 1 < 8) {
      gA = *(const u32x4*)(asrc + (ti + 1) * 64);
      const u16* bn2 = bsrc + (ti + 1) * 64;
      gB0 = *(const u32x4*)bn2;
      gB1 = *(const u32x4*)(bn2 + 8);
    }
#pragma unroll
    for (int kk = 0; kk < 2; kk++) {
      bf16x8 af[2], bf[2];
#pragma unroll
      for (int i = 0; i < 2; i++) {
        af[i] = *(const bf16x8*)&Alds[wm + i * 16 + lc][kk * 32 + g * 8];
        bf[i] = *(const bf16x8*)&Blds[wn + i * 16 + lc][kk * 32 + g * 8];
      }
#pragma unroll
      for (int mi = 0; mi < 2; mi++)
#pragma unroll
        for (int ni = 0; ni < 2; ni++)
          acc[mi][ni] = __builtin_amdgcn_mfma_f32_16x16x32_bf16(
              af[mi], bf[ni], acc[mi][ni], 0, 0, 0);
    }
  }

#pragma unroll
  for (int mi = 0; mi < 2; mi++)
#pragma unroll
    for (int ni = 0; ni < 2; ni++) {
      const int n = bn + wn + ni * 16 + lc;
      const float bv = bias[n];
#pragma unroll
      for (int j = 0; j < 4; j++) {
        const int m = bm + wm + mi * 16 + g * 4 + j;
        Cptr[(size_t)m * 512 + n] = acc[mi][ni][j] + bv;
      }
    }
}

// ---- flash attention: 8 waves, 64 q rows/block (grid 1024 = 4 blk/CU,
// 32 waves/CU), K=32 PV. Wave (wq=w>>1 in 0..3, wk=w&1) owns 16 q rows x
// 32-kv strip. Sync structure identical to R13/R18 (dbuf, 1 barrier/tile).
__global__ __launch_bounds__(512) void attn_kernel(
    const u16* __restrict__ Q, const u16* __restrict__ Kb,
    const u16* __restrict__ Vt, u16* __restrict__ Aout) {
  __shared__ __align__(16) char smem[37888];
  u16(*Kl)[64][72] = (u16(*)[64][72])smem;             // [2][64][72] 18432 B
  u16(*Vl)[64][72] = (u16(*)[64][72])(smem + 18432);   // [2][64][72] 18432 B
  float* lred = (float*)(smem + 36864);                // 128 f32 used
  float* Ol = (float*)smem;                            // epilogue alias 32 KB

  const int tid = threadIdx.x;
  const int w = tid >> 6, lane = tid & 63;
  const int g = (lane >> 4) & 3, lc = lane & 15;
  const int wq = w >> 1, wk = w & 1;

  // bijective XCD swizzle over 1024 blocks: XCD c gets bh [c*4, c*4+4)
  const int bid = blockIdx.x;
  const int swz = (bid & 7) * 128 + (bid >> 3);
  const int bh = swz >> 5;
  const int q0 = (swz & 31) * 64;

  // Q fragments (B-operand of QK): wave's 16 q rows
  bf16x8 qf[2];
  {
    const u16* qs =
        Q + ((size_t)bh * NL + q0 + wq * 16 + lc) * NE + g * 8;
    qf[0] = *(const bf16x8*)qs;
    qf[1] = *(const bf16x8*)(qs + 32);
  }

  f32x4 acc[4];  // acc[et]: O[q=wq*16+g*4+r][e=et*16+lc] (kv-strip partial)
#pragma unroll
  for (int i = 0; i < 4; i++) acc[i] = (f32x4){0.f, 0.f, 0.f, 0.f};
  float l = 0.f;

  // staging: 512 threads, 1 b128 each for K and V; K row-permuted (ksr)
  const int sr = tid >> 3, scc = (tid & 7) * 8;
  const int ksr =
      (sr & 32) + ((sr >> 2) & 1) * 16 + ((sr & 31) >> 3) * 4 + (sr & 3);
  const u16* kbase = Kb + ((size_t)bh * NL + sr) * NE + scc;
  const u16* vbase = Vt + ((size_t)bh * NE + sr) * NL + scc;

  // prologue: tile 0 -> buf 0
  u32x4 stg0 = *(const u32x4*)kbase;
  u32x4 stg1 = *(const u32x4*)vbase;
  *(u32x4*)&Kl[0][ksr][scc] = stg0;
  *(u32x4*)&Vl[0][sr][scc] = stg1;

  // hoisted read rows (storage-permuted K, natural V)
  const int krow0 = wk * 32 + lc;
  const int krow1 = wk * 32 + 16 + lc;
  const int vcol = wk * 32 + g * 8;

  for (int it = 0; it < NL / 64; ++it) {
    const int cur = it & 1;
    __syncthreads();
    if (it + 1 < NL / 64) {
      stg0 = *(const u32x4*)(kbase + (size_t)(it + 1) * 64 * NE);
      stg1 = *(const u32x4*)(vbase + (size_t)(it + 1) * 64);
    }

    bf16x8 ka[2][2];
    ka[0][0] = *(const bf16x8*)&Kl[cur][krow0][g * 8];
    ka[0][1] = *(const bf16x8*)&Kl[cur][krow0][32 + g * 8];
    ka[1][0] = *(const bf16x8*)&Kl[cur][krow1][g * 8];
    ka[1][1] = *(const bf16x8*)&Kl[cur][krow1][32 + g * 8];
    bf16x8 vf[4];
#pragma unroll
    for (int et = 0; et < 4; et++)
      vf[et] = *(const bf16x8*)&Vl[cur][et * 16 + lc][vcol];

    // QK^T (swapped): sc[n][r] = logit(kv=wk*32+g*8+n*4+r, q=wq*16+lc)
    f32x4 sc[2];
#pragma unroll
    for (int n = 0; n < 2; n++) {
      f32x4 z = (f32x4){0.f, 0.f, 0.f, 0.f};
      z = __builtin_amdgcn_mfma_f32_16x16x32_bf16(ka[n][0], qf[0], z, 0, 0, 0);
      z = __builtin_amdgcn_mfma_f32_16x16x32_bf16(ka[n][1], qf[1], z, 0, 0, 0);
      sc[n] = z;
    }

    // nomax softmax + bit-pack (round-half-up) + K=32 PV
    {
      float e[8];
#pragma unroll
      for (int n = 0; n < 2; n++)
#pragma unroll
        for (int r = 0; r < 4; r++)
          e[n * 4 + r] = __builtin_amdgcn_exp2f(sc[n][r]);
      l += ((e[0] + e[1]) + (e[2] + e[3])) + ((e[4] + e[5]) + (e[6] + e[7]));
      union { unsigned int u[4]; bf16x8 v; } pk;
#pragma unroll
      for (int k = 0; k < 4; k++) pk.u[k] = packbf(e[2 * k], e[2 * k + 1]);
#pragma unroll
      for (int et = 0; et < 4; et++)
        acc[et] = __builtin_amdgcn_mfma_f32_16x16x32_bf16(
            pk.v, vf[et], acc[et], 0, 0, 0);
    }

    if (it + 1 < NL / 64) {
      const int nxt = cur ^ 1;
      *(u32x4*)&Kl[nxt][ksr][scc] = stg0;
      *(u32x4*)&Vl[nxt][sr][scc] = stg1;
    }
  }

  // ---- epilogue: combine partials across wk pairs ----
  {
    float s = l;
    s += __shfl_xor(s, 16);
    s += __shfl_xor(s, 32);
    if (lane < 16) lred[w * 16 + lc] = s;
  }
  __syncthreads();  // also: all main-loop LDS reads complete -> alias safe

  const float invl =
      1.0f / (lred[(wq * 2 + 0) * 16 + lc] + lred[(wq * 2 + 1) * 16 + lc]);

  const int b = bh >> 3, h = bh & 7;
#pragma unroll
  for (int et = 0; et < 4; et++) {
    const int off = ((w * 4 + et) * 4 + g) * 64 + lc * 4;
    *(f32x4*)&Ol[off] = acc[et];
  }
  __syncthreads();
#pragma unroll
  for (int i = 0; i < 2; i++) {
    const int et2 = wk * 2 + i;
    const int o0 = (((wq * 2 + 0) * 4 + et2) * 4 + g) * 64 + lc * 4;
    const int o1 = (((wq * 2 + 1) * 4 + et2) * 4 + g) * 64 + lc * 4;
    f32x4 t0 = *(const f32x4*)&Ol[o0];
    f32x4 t1 = *(const f32x4*)&Ol[o1];
#pragma unroll
    for (int r = 0; r < 4; r++) {
      const float ir = __shfl(invl, (lane & 48) | (g * 4 + r));
      Aout[((size_t)(b * NL) + q0 + wq * 16 + g * 4 + r) * DM + h * NE +
           et2 * 16 + lc] = f2bf((t0[r] + t1[r]) * ir);
    }
  }
}

extern "C" void kernel_launch(void* const* d_in, const int* in_sizes, int n_in,
                              void* d_out, int out_size, void* d_ws,
                              size_t ws_size, hipStream_t stream) {
  const float* queries = (const float*)d_in[0];
  const float* keys = (const float*)d_in[1];
  const float* values = (const float*)d_in[2];
  const float* Wq = (const float*)d_in[3];
  const float* bq = (const float*)d_in[4];
  const float* Wk = (const float*)d_in[5];
  const float* bk = (const float*)d_in[6];
  const float* Wv = (const float*)d_in[7];
  const float* bv = (const float*)d_in[8];
  const float* Wo = (const float*)d_in[9];
  const float* bo = (const float*)d_in[10];

  u16* wq_t = (u16*)d_ws;
  u16* wk_t = wq_t + 512 * 512;
  u16* wv_t = wk_t + 512 * 512;
  u16* wo_t = wv_t + 512 * 512;
  u16* qb = wo_t + 512 * 512;
  u16* kbuf = qb + (size_t)NBH * NL * NE;
  u16* vtb = kbuf + (size_t)NBH * NL * NE;
  u16* ab = vtb + (size_t)NBH * NL * NE;

  dim3 tgrid(16, 16, 4);
  wt_kernel<<<tgrid, 256, 0, stream>>>(Wq, Wk, Wv, Wo, wq_t, wk_t, wv_t, wo_t);

  dim3 ggrid(128, 4, 3);
  qkv_kernel<<<ggrid, 512, 0, stream>>>(queries, keys, values, wq_t, wk_t,
                                        wv_t, bq, bk, bv, qb, kbuf, vtb);

  attn_kernel<<<dim3(1024), 512, 0, stream>>>(qb, kbuf, vtb, ab);

  dim3 ogrid(128, 4);
  gemm_out_kernel<<<ogrid, 512, 0, stream>>>(ab, wo_t, bo, (float*)d_out);
}

// Round 20
// 96.369 us; speedup vs baseline: 1.0697x; 1.0697x over previous
//
#include <hip/hip_runtime.h>
#include <hip/hip_bf16.h>

#define DI 512
#define DM 512
#define NBATCH 4
#define NL 2048
#define NH 8
#define NE 64
#define NBH 32   // NBATCH*NH

typedef __attribute__((ext_vector_type(8))) short bf16x8;
typedef __attribute__((ext_vector_type(4))) short bf16x4;
typedef __attribute__((ext_vector_type(4))) float f32x4;
typedef __attribute__((ext_vector_type(4))) float fx4;
typedef __attribute__((ext_vector_type(4))) unsigned int u32x4;
typedef unsigned short u16;

__device__ __forceinline__ u16 f2bf(float f) {
  union { float f; unsigned int u; } v; v.f = f;
  unsigned int r = v.u + 0x7fffu + ((v.u >> 16) & 1u);
  return (u16)(r >> 16);
}

__device__ __forceinline__ unsigned int packbf(float lo, float hi) {
  const unsigned int l = __float_as_uint(lo) + 0x8000u;
  const unsigned int h = __float_as_uint(hi) + 0x8000u;
  return (h & 0xFFFF0000u) | (l >> 16);
}

// ---- weight transpose + f32->bf16, all 4 weights in one launch ----
__global__ __launch_bounds__(256) void wt_kernel(
    const float* __restrict__ W0, const float* __restrict__ W1,
    const float* __restrict__ W2, const float* __restrict__ W3,
    u16* __restrict__ T0, u16* __restrict__ T1, u16* __restrict__ T2,
    u16* __restrict__ T3) {
  const int z = blockIdx.z;
  const float* W = z == 0 ? W0 : z == 1 ? W1 : z == 2 ? W2 : W3;
  u16* Wt = z == 0 ? T0 : z == 1 ? T1 : z == 2 ? T2 : T3;
  __shared__ float t[32][33];
  const int bk = blockIdx.x * 32;
  const int bn = blockIdx.y * 32;
  const int x = threadIdx.x & 31;
  const int y0 = (threadIdx.x >> 5) * 4;
#pragma unroll
  for (int i = 0; i < 4; i++)
    t[y0 + i][x] = W[(size_t)(bk + y0 + i) * 512 + bn + x];
  __syncthreads();
#pragma unroll
  for (int i = 0; i < 4; i++)
    Wt[(size_t)(bn + y0 + i) * 512 + bk + x] = f2bf(t[x][y0 + i]);
}

// ---- QKV projections: 64x128 tile, 512 threads / 8 waves (R18-proven) ----
__global__ __launch_bounds__(512) void qkv_kernel(
    const float* __restrict__ Aq, const float* __restrict__ Ak,
    const float* __restrict__ Av, const u16* __restrict__ Bq,
    const u16* __restrict__ Bk, const u16* __restrict__ Bv,
    const float* __restrict__ biq, const float* __restrict__ bik,
    const float* __restrict__ biv, u16* __restrict__ oq,
    u16* __restrict__ ok, u16* __restrict__ ov) {
  const int z = blockIdx.z;
  const float* A = z == 0 ? Aq : z == 1 ? Ak : Av;
  const u16* Bt = z == 0 ? Bq : z == 1 ? Bk : Bv;
  const float* bias = z == 0 ? biq : z == 1 ? bik : biv;
  u16* Cptr = z == 0 ? oq : z == 1 ? ok : ov;
  const float scale = z == 0 ? 0.1803368867f : 1.0f;  // 0.125/ln(2) for q

  __shared__ u16 Alds[64][72];
  __shared__ u16 Blds[128][72];
  const int tid = threadIdx.x;
  const int w = tid >> 6, lane = tid & 63;
  const int g = lane >> 4, lc = lane & 15;
  const int bm = blockIdx.x * 64;
  const int bn = blockIdx.y * 128;
  const int wm = (w >> 2) * 32;
  const int wn = (w & 3) * 32;

  f32x4 acc[2][2];
#pragma unroll
  for (int i = 0; i < 2; i++)
#pragma unroll
    for (int j = 0; j < 2; j++) acc[i][j] = (f32x4){0.f, 0.f, 0.f, 0.f};

  const int ar = tid >> 3, ac = (tid & 7) * 8;    // A: 64 rows, 8 f32/thr
  const int br = tid >> 2, bc = (tid & 3) * 16;   // B: 128 rows, 16 bf16/thr

  const float* asrc = A + (size_t)(bm + ar) * 512 + ac;
  const u16* bsrc = Bt + (size_t)(bn + br) * 512 + bc;

  fx4 fA0 = *(const fx4*)asrc;
  fx4 fA1 = *(const fx4*)(asrc + 4);
  u32x4 fB0 = *(const u32x4*)bsrc;
  u32x4 fB1 = *(const u32x4*)(bsrc + 8);

#pragma unroll
  for (int ti = 0; ti < 8; ++ti) {
    __syncthreads();  // prev compute's LDS reads complete
    {
      u32x4 out;
      out[0] = packbf(fA0[0], fA0[1]);
      out[1] = packbf(fA0[2], fA0[3]);
      out[2] = packbf(fA1[0], fA1[1]);
      out[3] = packbf(fA1[2], fA1[3]);
      *(u32x4*)&Alds[ar][ac] = out;
      *(u32x4*)&Blds[br][bc] = fB0;
      *(u32x4*)&Blds[br][bc + 8] = fB1;
    }
    __syncthreads();  // writes visible
    if (ti + 1 < 8) {  // issue next-tile loads; hide under compute
      const float* an = asrc + (ti + 1) * 64;
      fA0 = *(const fx4*)an;
      fA1 = *(const fx4*)(an + 4);
      const u16* bn2 = bsrc + (ti + 1) * 64;
      fB0 = *(const u32x4*)bn2;
      fB1 = *(const u32x4*)(bn2 + 8);
    }
#pragma unroll
    for (int kk = 0; kk < 2; kk++) {
      bf16x8 af[2], bf[2];
#pragma unroll
      for (int i = 0; i < 2; i++) {
        af[i] = *(const bf16x8*)&Alds[wm + i * 16 + lc][kk * 32 + g * 8];
        bf[i] = *(const bf16x8*)&Blds[wn + i * 16 + lc][kk * 32 + g * 8];
      }
#pragma unroll
      for (int mi = 0; mi < 2; mi++)
#pragma unroll
        for (int ni = 0; ni < 2; ni++)
          acc[mi][ni] = __builtin_amdgcn_mfma_f32_16x16x32_bf16(
              af[mi], bf[ni], acc[mi][ni], 0, 0, 0);
    }
  }

#pragma unroll
  for (int mi = 0; mi < 2; mi++)
#pragma unroll
    for (int ni = 0; ni < 2; ni++) {
      const int n = bn + wn + ni * 16 + lc;
      const float bv = bias[n];
#pragma unroll
      for (int j = 0; j < 4; j++) {
        const int m = bm + wm + mi * 16 + g * 4 + j;
        float val = (acc[mi][ni][j] + bv) * scale;
        const int b = m >> 11, l = m & 2047;
        const int h = n >> 6, e = n & 63;
        if (z < 2) {
          Cptr[((size_t)(b * NH + h) * NL + l) * NE + e] = f2bf(val);
        } else {
          Cptr[((size_t)(b * NH + h) * NE + e) * NL + l] = f2bf(val);
        }
      }
    }
}

// ---- output projection: 64x128 tile, 512 threads / 8 waves (R18) ----
__global__ __launch_bounds__(512) void gemm_out_kernel(
    const u16* __restrict__ A, const u16* __restrict__ Bt,
    const float* __restrict__ bias, float* __restrict__ Cptr) {
  __shared__ u16 Alds[64][72];
  __shared__ u16 Blds[128][72];
  const int tid = threadIdx.x;
  const int w = tid >> 6, lane = tid & 63;
  const int g = lane >> 4, lc = lane & 15;
  const int bm = blockIdx.x * 64;
  const int bn = blockIdx.y * 128;
  const int wm = (w >> 2) * 32;
  const int wn = (w & 3) * 32;

  f32x4 acc[2][2];
#pragma unroll
  for (int i = 0; i < 2; i++)
#pragma unroll
    for (int j = 0; j < 2; j++) acc[i][j] = (f32x4){0.f, 0.f, 0.f, 0.f};

  const int ar = tid >> 3, ac = (tid & 7) * 8;
  const int br = tid >> 2, bc = (tid & 3) * 16;

  const u16* asrc = A + (size_t)(bm + ar) * 512 + ac;
  const u16* bsrc = Bt + (size_t)(bn + br) * 512 + bc;

  u32x4 gA = *(const u32x4*)asrc;
  u32x4 gB0 = *(const u32x4*)bsrc;
  u32x4 gB1 = *(const u32x4*)(bsrc + 8);

#pragma unroll
  for (int ti = 0; ti < 8; ++ti) {
    __syncthreads();
    {
      *(u32x4*)&Alds[ar][ac] = gA;
      *(u32x4*)&Blds[br][bc] = gB0;
      *(u32x4*)&Blds[br][bc + 8] = gB1;
    }
    __syncthreads();
    if (ti + 1 < 8) {
      gA = *(const u32x4*)(asrc + (ti + 1) * 64);
      const u16* bn2 = bsrc + (ti + 1) * 64;
      gB0 = *(const u32x4*)bn2;
      gB1 = *(const u32x4*)(bn2 + 8);
    }
#pragma unroll
    for (int kk = 0; kk < 2; kk++) {
      bf16x8 af[2], bf[2];
#pragma unroll
      for (int i = 0; i < 2; i++) {
        af[i] = *(const bf16x8*)&Alds[wm + i * 16 + lc][kk * 32 + g * 8];
        bf[i] = *(const bf16x8*)&Blds[wn + i * 16 + lc][kk * 32 + g * 8];
      }
#pragma unroll
      for (int mi = 0; mi < 2; mi++)
#pragma unroll
        for (int ni = 0; ni < 2; ni++)
          acc[mi][ni] = __builtin_amdgcn_mfma_f32_16x16x32_bf16(
              af[mi], bf[ni], acc[mi][ni], 0, 0, 0);
    }
  }

#pragma unroll
  for (int mi = 0; mi < 2; mi++)
#pragma unroll
    for (int ni = 0; ni < 2; ni++) {
      const int n = bn + wn + ni * 16 + lc;
      const float bv = bias[n];
#pragma unroll
      for (int j = 0; j < 4; j++) {
        const int m = bm + wm + mi * 16 + g * 4 + j;
        Cptr[(size_t)m * 512 + n] = acc[mi][ni][j] + bv;
      }
    }
}

// ---- flash attention: 8 waves, 128 q rows/block, K=32 PV (R18-proven) ----
__global__ __launch_bounds__(512) void attn_kernel(
    const u16* __restrict__ Q, const u16* __restrict__ Kb,
    const u16* __restrict__ Vt, u16* __restrict__ Aout) {
  __shared__ __align__(16) char smem[37888];
  u16(*Kl)[64][72] = (u16(*)[64][72])smem;             // [2][64][72] 18432 B
  u16(*Vl)[64][72] = (u16(*)[64][72])(smem + 18432);   // [2][64][72] 18432 B
  float* lred = (float*)(smem + 36864);                // 256 f32
  float* Ol = (float*)smem;                            // epilogue alias 32 KB

  const int tid = threadIdx.x;
  const int w = tid >> 6, lane = tid & 63;
  const int g = (lane >> 4) & 3, lc = lane & 15;
  const int wq = w >> 1, wk = w & 1;

  // bijective XCD swizzle over 512 blocks: XCD c gets bh [c*4, c*4+4)
  const int bid = blockIdx.x;
  const int swz = (bid & 7) * 64 + (bid >> 3);
  const int bh = swz >> 4;
  const int q0 = (swz & 15) * 128;

  // Q fragments (B-operand of QK) for this wave's 2 q sub-blocks
  bf16x8 qf[2][2];
#pragma unroll
  for (int qb = 0; qb < 2; qb++) {
    const u16* qs =
        Q + ((size_t)bh * NL + q0 + wq * 32 + qb * 16 + lc) * NE + g * 8;
    qf[qb][0] = *(const bf16x8*)qs;
    qf[qb][1] = *(const bf16x8*)(qs + 32);
  }

  f32x4 acc[2][4];  // acc[qb][et]: O[q=wq*32+qb*16+g*4+r][e=et*16+lc] partial
#pragma unroll
  for (int a = 0; a < 2; a++)
#pragma unroll
    for (int b2 = 0; b2 < 4; b2++) acc[a][b2] = (f32x4){0.f, 0.f, 0.f, 0.f};
  float l[2] = {0.f, 0.f};

  // staging: 512 threads, 1 b128 each for K and V; K row-permuted (ksr)
  const int sr = tid >> 3, scc = (tid & 7) * 8;
  const int ksr =
      (sr & 32) + ((sr >> 2) & 1) * 16 + ((sr & 31) >> 3) * 4 + (sr & 3);
  const u16* kbase = Kb + ((size_t)bh * NL + sr) * NE + scc;
  const u16* vbase = Vt + ((size_t)bh * NE + sr) * NL + scc;

  // prologue: tile 0 -> buf 0
  u32x4 stg0 = *(const u32x4*)kbase;
  u32x4 stg1 = *(const u32x4*)vbase;
  *(u32x4*)&Kl[0][ksr][scc] = stg0;
  *(u32x4*)&Vl[0][sr][scc] = stg1;

  // hoisted read rows (storage-permuted K, natural V)
  const int krow0 = wk * 32 + lc;
  const int krow1 = wk * 32 + 16 + lc;
  const int vcol = wk * 32 + g * 8;

  for (int it = 0; it < NL / 64; ++it) {
    const int cur = it & 1;
    __syncthreads();
    if (it + 1 < NL / 64) {
      stg0 = *(const u32x4*)(kbase + (size_t)(it + 1) * 64 * NE);
      stg1 = *(const u32x4*)(vbase + (size_t)(it + 1) * 64);
    }

    bf16x8 ka[2][2];
    ka[0][0] = *(const bf16x8*)&Kl[cur][krow0][g * 8];
    ka[0][1] = *(const bf16x8*)&Kl[cur][krow0][32 + g * 8];
    ka[1][0] = *(const bf16x8*)&Kl[cur][krow1][g * 8];
    ka[1][1] = *(const bf16x8*)&Kl[cur][krow1][32 + g * 8];
    bf16x8 vf[4];
#pragma unroll
    for (int et = 0; et < 4; et++)
      vf[et] = *(const bf16x8*)&Vl[cur][et * 16 + lc][vcol];

    // QK^T (swapped): sc[qb][n][r] = logit(kv=wk*32+g*8+n*4+r, q=..+lc)
    f32x4 sc[2][2];
#pragma unroll
    for (int qb = 0; qb < 2; qb++)
#pragma unroll
      for (int n = 0; n < 2; n++) {
        f32x4 z = (f32x4){0.f, 0.f, 0.f, 0.f};
        z = __builtin_amdgcn_mfma_f32_16x16x32_bf16(ka[n][0], qf[qb][0], z, 0, 0, 0);
        z = __builtin_amdgcn_mfma_f32_16x16x32_bf16(ka[n][1], qf[qb][1], z, 0, 0, 0);
        sc[qb][n] = z;
      }

    // nomax softmax + bit-pack (round-half-up) + K=32 PV
#pragma unroll
    for (int qb = 0; qb < 2; qb++) {
      float e[8];
#pragma unroll
      for (int n = 0; n < 2; n++)
#pragma unroll
        for (int r = 0; r < 4; r++)
          e[n * 4 + r] = __builtin_amdgcn_exp2f(sc[qb][n][r]);
      l[qb] += ((e[0] + e[1]) + (e[2] + e[3])) +
               ((e[4] + e[5]) + (e[6] + e[7]));
      union { unsigned int u[4]; bf16x8 v; } pk;
#pragma unroll
      for (int k = 0; k < 4; k++) pk.u[k] = packbf(e[2 * k], e[2 * k + 1]);
#pragma unroll
      for (int et = 0; et < 4; et++)
        acc[qb][et] = __builtin_amdgcn_mfma_f32_16x16x32_bf16(
            pk.v, vf[et], acc[qb][et], 0, 0, 0);
    }

    if (it + 1 < NL / 64) {
      const int nxt = cur ^ 1;
      *(u32x4*)&Kl[nxt][ksr][scc] = stg0;
      *(u32x4*)&Vl[nxt][sr][scc] = stg1;
    }
  }

  // ---- epilogue: combine partials across wk pairs ----
#pragma unroll
  for (int qb = 0; qb < 2; qb++) {
    float s = l[qb];
    s += __shfl_xor(s, 16);
    s += __shfl_xor(s, 32);
    if (lane < 16) lred[(w * 2 + qb) * 16 + lc] = s;
  }
  __syncthreads();

  float invl[2];
#pragma unroll
  for (int qb = 0; qb < 2; qb++)
    invl[qb] = 1.0f / (lred[((wq * 2 + 0) * 2 + qb) * 16 + lc] +
                       lred[((wq * 2 + 1) * 2 + qb) * 16 + lc]);

  const int b = bh >> 3, h = bh & 7;
#pragma unroll
  for (int qb = 0; qb < 2; qb++) {
    __syncthreads();  // prior pass / main-loop LDS reads complete
#pragma unroll
    for (int et = 0; et < 4; et++) {
      const int off = ((w * 4 + et) * 4 + g) * 64 + lc * 4;
      *(f32x4*)&Ol[off] = acc[qb][et];
    }
    __syncthreads();
#pragma unroll
    for (int i = 0; i < 2; i++) {
      const int et2 = wk * 2 + i;
      const int o0 = (((wq * 2 + 0) * 4 + et2) * 4 + g) * 64 + lc * 4;
      const int o1 = (((wq * 2 + 1) * 4 + et2) * 4 + g) * 64 + lc * 4;
      f32x4 t0 = *(const f32x4*)&Ol[o0];
      f32x4 t1 = *(const f32x4*)&Ol[o1];
#pragma unroll
      for (int r = 0; r < 4; r++) {
        const float ir = __shfl(invl[qb], (lane & 48) | (g * 4 + r));
        Aout[((size_t)(b * NL) + q0 + wq * 32 + qb * 16 + g * 4 + r) * DM +
             h * NE + et2 * 16 + lc] = f2bf((t0[r] + t1[r]) * ir);
      }
    }
  }
}

extern "C" void kernel_launch(void* const* d_in, const int* in_sizes, int n_in,
                              void* d_out, int out_size, void* d_ws,
                              size_t ws_size, hipStream_t stream) {
  const float* queries = (const float*)d_in[0];
  const float* keys = (const float*)d_in[1];
  const float* values = (const float*)d_in[2];
  const float* Wq = (const float*)d_in[3];
  const float* bq = (const float*)d_in[4];
  const float* Wk = (const float*)d_in[5];
  const float* bk = (const float*)d_in[6];
  const float* Wv = (const float*)d_in[7];
  const float* bv = (const float*)d_in[8];
  const float* Wo = (const float*)d_in[9];
  const float* bo = (const float*)d_in[10];

  u16* wq_t = (u16*)d_ws;
  u16* wk_t = wq_t + 512 * 512;
  u16* wv_t = wk_t + 512 * 512;
  u16* wo_t = wv_t + 512 * 512;
  u16* qb = wo_t + 512 * 512;
  u16* kbuf = qb + (size_t)NBH * NL * NE;
  u16* vtb = kbuf + (size_t)NBH * NL * NE;
  u16* ab = vtb + (size_t)NBH * NL * NE;

  dim3 tgrid(16, 16, 4);
  wt_kernel<<<tgrid, 256, 0, stream>>>(Wq, Wk, Wv, Wo, wq_t, wk_t, wv_t, wo_t);

  dim3 ggrid(128, 4, 3);
  qkv_kernel<<<ggrid, 512, 0, stream>>>(queries, keys, values, wq_t, wk_t,
                                        wv_t, bq, bk, bv, qb, kbuf, vtb);

  attn_kernel<<<dim3(512), 512, 0, stream>>>(qb, kbuf, vtb, ab);

  dim3 ogrid(128, 4);
  gemm_out_kernel<<<ogrid, 512, 0, stream>>>(ab, wo_t, bo, (float*)d_out);
}